// Round 16
// baseline (527.226 us; speedup 1.0000x reference)
//
#include <hip/hip_runtime.h>
#include <cmath>

#define NN 100000
#define NE 3200000
#define TT 2048
#define MM 256
#define STR 16    // padded row stride (floats) for fp32 node arrays -> 64B rows
#define HSTR 16   // row stride (ushorts) for bf16 rows -> 32B, 3.2MB/array
#define BSZ 64    // nodes per bucket
#define NB 1563   // ceil(NN/BSZ)
#define EPB 16384 // edges per scatter block
#define NBLK 196  // ceil(NE/EPB)
#define SCAP 3072 // max valid edges per bucket (mean 2048, 12+ sigma margin)
#define PCAP 4096 // fixed padded region per bucket in srtp (padded mean ~3126)
#define CMAX 12   // max edges per lane chunk in gather

__device__ __forceinline__ void atomicMaxF(float* addr, float v) {
    if (v >= 0.f) atomicMax((int*)addr, __float_as_int(v));
    else          atomicMin((unsigned int*)addr, __float_as_uint(v));
}

__device__ __forceinline__ unsigned short f2bf(float x) {
    unsigned u = __float_as_uint(x);
    u += 0x7FFFu + ((u >> 16) & 1u);   // round-to-nearest-even
    return (unsigned short)(u >> 16);
}

__device__ __forceinline__ void unpack10(uint4 q, unsigned q2, float* a) {
    a[0] = __uint_as_float(q.x << 16);
    a[1] = __uint_as_float(q.x & 0xFFFF0000u);
    a[2] = __uint_as_float(q.y << 16);
    a[3] = __uint_as_float(q.y & 0xFFFF0000u);
    a[4] = __uint_as_float(q.z << 16);
    a[5] = __uint_as_float(q.z & 0xFFFF0000u);
    a[6] = __uint_as_float(q.w << 16);
    a[7] = __uint_as_float(q.w & 0xFFFF0000u);
    a[8] = __uint_as_float(q2 << 16);
    a[9] = __uint_as_float(q2 & 0xFFFF0000u);
}

// ---------------- init (pcursor/amax/Vsum) + layer-1 prep fused ----------------
__global__ __launch_bounds__(256) void init_prep1_kernel(
    const float* __restrict__ x1,
    const float* __restrict__ Wl, const float* __restrict__ bl,
    const float* __restrict__ Wr, const float* __restrict__ br,
    unsigned short* __restrict__ xlh, unsigned short* __restrict__ xrh,
    int* __restrict__ pcursor, float* __restrict__ Vsum)
{
    __shared__ float sWl[150], sWr[150], sbl[10], sbr[10];
    int tid = threadIdx.x;
    for (int i = tid; i < 150; i += 256) { sWl[i] = Wl[i]; sWr[i] = Wr[i]; }
    if (tid < 10) { sbl[tid] = bl[tid]; sbr[tid] = br[tid]; }
    __syncthreads();
    int gid = blockIdx.x * 256 + tid;
    if (gid < NB) pcursor[gid] = gid * PCAP;
    if (gid == 0) Vsum[0] = 0.f;
    int n = gid;
    if (n >= NN) return;

    float in[15];
    #pragma unroll
    for (int k = 0; k < 15; k++) in[k] = x1[n * 15 + k];

    unsigned* lp = (unsigned*)(xlh + n * HSTR);
    unsigned* rp = (unsigned*)(xrh + n * HSTR);
    #pragma unroll
    for (int jp = 0; jp < 5; jp++) {
        float sl0 = sbl[2 * jp], sr0 = sbr[2 * jp];
        float sl1 = sbl[2 * jp + 1], sr1 = sbr[2 * jp + 1];
        for (int k = 0; k < 15; k++) {
            float v = in[k];
            sl0 += v * sWl[(2 * jp) * 15 + k];
            sr0 += v * sWr[(2 * jp) * 15 + k];
            sl1 += v * sWl[(2 * jp + 1) * 15 + k];
            sr1 += v * sWr[(2 * jp + 1) * 15 + k];
        }
        lp[jp] = (unsigned)f2bf(sl0) | ((unsigned)f2bf(sl1) << 16);
        rp[jp] = (unsigned)f2bf(sr0) | ((unsigned)f2bf(sr1) << 16);
    }
}

// ---------------- scatter: LDS counting-sort by bucket, burst int4 writes ----------
__global__ __launch_bounds__(1024) void scatter_kernel(const int* __restrict__ src,
                                                       const int* __restrict__ dst,
                                                       int* __restrict__ pcursor,
                                                       int* __restrict__ srtp) {
    __shared__ int ent[EPB];
    __shared__ int cnt[NB];
    __shared__ int cur[NB];
    __shared__ int gbase[NB];
    __shared__ int psc[1024];
    int tid = threadIdx.x;
    for (int i = tid; i < NB; i += 1024) cnt[i] = 0;
    __syncthreads();
    int base = blockIdx.x * EPB;
    int end = base + EPB; if (end > NE) end = NE;
    for (int i = base + tid * 4; i < end; i += 4096) {
        int4 d4 = *(const int4*)(dst + i);
        atomicAdd(&cnt[d4.x >> 6], 1);
        atomicAdd(&cnt[d4.y >> 6], 1);
        atomicAdd(&cnt[d4.z >> 6], 1);
        atomicAdd(&cnt[d4.w >> 6], 1);
    }
    __syncthreads();
    const int PT = (NB + 1023) / 1024;  // 2
    int t0 = tid * PT;
    int s = 0;
    #pragma unroll
    for (int j = 0; j < PT; j++) { int idx = t0 + j; if (idx < NB) s += cnt[idx]; }
    psc[tid] = s;
    __syncthreads();
    for (int off = 1; off < 1024; off <<= 1) {
        int v = (tid >= off) ? psc[tid - off] : 0;
        __syncthreads();
        psc[tid] += v;
        __syncthreads();
    }
    int run = psc[tid] - s;
    #pragma unroll
    for (int j = 0; j < PT; j++) {
        int idx = t0 + j;
        if (idx < NB) { cur[idx] = run; run += cnt[idx]; }
    }
    for (int b = tid; b < NB; b += 1024) {
        int n = cnt[b];
        gbase[b] = n ? atomicAdd(&pcursor[b], (n + 15) & ~15) : 0;
    }
    __syncthreads();
    for (int i = base + tid * 4; i < end; i += 4096) {
        int4 d4 = *(const int4*)(dst + i);
        int4 s4 = *(const int4*)(src + i);
        int d, b, off;
        d = d4.x; b = d >> 6; off = atomicAdd(&cur[b], 1); ent[off] = ((d & 63) << 17) | s4.x;
        d = d4.y; b = d >> 6; off = atomicAdd(&cur[b], 1); ent[off] = ((d & 63) << 17) | s4.y;
        d = d4.z; b = d >> 6; off = atomicAdd(&cur[b], 1); ent[off] = ((d & 63) << 17) | s4.z;
        d = d4.w; b = d >> 6; off = atomicAdd(&cur[b], 1); ent[off] = ((d & 63) << 17) | s4.w;
    }
    __syncthreads();
    for (int b = tid; b < NB; b += 1024) {
        int n = cnt[b];
        if (!n) continue;
        int lb = cur[b] - n;
        int gb = gbase[b];
        int p16 = (n + 15) & ~15;
        for (int k = 0; k < p16; k += 4) {
            int4 v;
            v.x = (k + 0 < n) ? ent[lb + k + 0] : -1;
            v.y = (k + 1 < n) ? ent[lb + k + 1] : -1;
            v.z = (k + 2 < n) ? ent[lb + k + 2] : -1;
            v.w = (k + 3 < n) ? ent[lb + k + 3] : -1;
            *(int4*)(srtp + gb + k) = v;
        }
    }
}

// ---------------- sort2: in-LDS counting sort by local dst, compact IN PLACE ----------
__global__ __launch_bounds__(512) void sort2_kernel(int* __restrict__ srtp,
                                                    const int* __restrict__ pcursor,
                                                    int* __restrict__ bcounts) {
    __shared__ int ent[PCAP];
    __shared__ int ent2[SCAP];
    __shared__ int cnts[BSZ];
    __shared__ int curs[BSZ];
    int b = blockIdx.x, tid = threadIdx.x;
    int p0 = b * PCAP;
    int pcnt = pcursor[b] - p0;
    if (pcnt > PCAP) pcnt = PCAP;
    if (tid < BSZ) cnts[tid] = 0;
    __syncthreads();
    for (int i = tid; i < pcnt; i += 512) {
        int p = srtp[p0 + i];
        ent[i] = p;
        if (p >= 0) atomicAdd(&cnts[p >> 17], 1);
    }
    __syncthreads();
    if (tid == 0) {
        int run = 0;
        for (int k = 0; k < BSZ; k++) { curs[k] = run; run += cnts[k]; }
    }
    __syncthreads();
    for (int i = tid; i < pcnt; i += 512) {
        int p = ent[i];
        if (p >= 0) {
            int pos = atomicAdd(&curs[p >> 17], 1);
            ent2[pos] = p;
        }
    }
    __syncthreads();
    int cnt = curs[BSZ - 1];   // total valid
    for (int i = tid; i < cnt; i += 512) srtp[p0 + i] = ent2[i];
    if (tid == 0) bcounts[b] = cnt;
}

// ---------------- gather mid: R10 main loop (depth-1) + lane-parallel fused prep ----
__global__ __launch_bounds__(256, 4) void gather_mid_kernel(
    const int* __restrict__ srtp, const int* __restrict__ bcounts,
    const unsigned short* __restrict__ xlh, const unsigned short* __restrict__ xrh,
    const float* __restrict__ att, const float* __restrict__ bias,
    const float* __restrict__ x1,
    const float* __restrict__ Wl2, const float* __restrict__ bl2,
    const float* __restrict__ Wr2, const float* __restrict__ br2,
    unsigned short* __restrict__ xlh_out, unsigned short* __restrict__ xrh_out)
{
    __shared__ float accs[BSZ * 11];
    __shared__ float xrs[BSZ * 11];
    __shared__ float sat[10], sbias[10];
    __shared__ float sWl2[250], sWr2[250], sbl2[10], sbr2[10];
    __shared__ float inbuf[BSZ * 25];   // [node][0..9]=h, [10..24]=x1
    int b = blockIdx.x, tid = threadIdx.x;
    int n0 = b * BSZ;
    int nv = NN - n0; if (nv > BSZ) nv = BSZ;
    if (tid < 10) { sat[tid] = att[tid]; sbias[tid] = bias[tid];
                    sbl2[tid] = bl2[tid]; sbr2[tid] = br2[tid]; }
    for (int i = tid; i < 250; i += 256) { sWl2[i] = Wl2[i]; sWr2[i] = Wr2[i]; }
    for (int i = tid; i < nv * 15; i += 256)
        inbuf[(i / 15) * 25 + 10 + (i % 15)] = x1[n0 * 15 + i];
    __syncthreads();

    if (tid < BSZ) {
        int n = n0 + tid;
        if (n < NN) {
            const unsigned short* lr = xlh + n * HSTR;
            const unsigned short* rr = xrh + n * HSTR;
            uint4 ql = *(const uint4*)lr;  unsigned ql2 = *(const unsigned*)(lr + 8);
            uint4 qr = *(const uint4*)rr;  unsigned qr2 = *(const unsigned*)(rr + 8);
            float a[10], r[10];
            unpack10(ql, ql2, a);
            unpack10(qr, qr2, r);
            #pragma unroll
            for (int k = 0; k < 10; k++) xrs[tid * 11 + k] = r[k];
            float e = 0.f;
            #pragma unroll
            for (int k = 0; k < 10; k++) {
                float t = a[k] + r[k];
                t = t > 0.f ? t : 0.2f * t;
                e += sat[k] * t;
            }
            float ex = __expf(e);
            #pragma unroll
            for (int k = 0; k < 10; k++) accs[tid * 11 + k] = ex * a[k];
            accs[tid * 11 + 10] = ex;
        } else {
            #pragma unroll
            for (int k = 0; k < 11; k++) { accs[tid * 11 + k] = 0.f; xrs[tid * 11 + k] = 0.f; }
        }
    }
    __syncthreads();

    int i0 = b * PCAP;
    int cnt = bcounts[b];
    int C = (cnt + 255) >> 8;
    int a0 = i0 + tid * C;
    int a1 = a0 + C; if (a1 > i0 + cnt) a1 = i0 + cnt;
    int len = a1 - a0; if (len < 0) len = 0;
    if (len > 0) {
        int ps[CMAX];
        #pragma unroll
        for (int i = 0; i < CMAX; i++) ps[i] = (i < len) ? srtp[a0 + i] : -1;

        const unsigned short* row0 = xlh + (ps[0] & 0x1FFFF) * HSTR;
        uint4 q = *(const uint4*)row0;
        unsigned q2 = *(const unsigned*)(row0 + 8);
        int cur = ps[0] >> 17;
        float racc[10];
        #pragma unroll
        for (int k = 0; k < 10; k++) racc[k] = 0.f;
        float rden = 0.f;
        #pragma unroll
        for (int i = 0; i < CMAX; i++) {
            if (i >= len) break;
            uint4 qn = q; unsigned q2n = q2;
            if (i + 1 < len) {
                const unsigned short* rn = xlh + (ps[i + 1] & 0x1FFFF) * HSTR;
                qn = *(const uint4*)rn;
                q2n = *(const unsigned*)(rn + 8);
            }
            int ld = ps[i] >> 17;
            if (ld != cur) {
                float* ac = accs + cur * 11;
                #pragma unroll
                for (int k = 0; k < 10; k++) atomicAdd(ac + k, racc[k]);
                atomicAdd(ac + 10, rden);
                #pragma unroll
                for (int k = 0; k < 10; k++) racc[k] = 0.f;
                rden = 0.f;
                cur = ld;
            }
            float a[10];
            unpack10(q, q2, a);
            const float* r = xrs + ld * 11;
            float e = 0.f;
            #pragma unroll
            for (int k = 0; k < 10; k++) {
                float t = a[k] + r[k];
                t = t > 0.f ? t : 0.2f * t;
                e += sat[k] * t;
            }
            float ex = __expf(e);
            rden += ex;
            #pragma unroll
            for (int k = 0; k < 10; k++) racc[k] += ex * a[k];
            q = qn; q2 = q2n;
        }
        float* ac = accs + cur * 11;
        #pragma unroll
        for (int k = 0; k < 10; k++) atomicAdd(ac + k, racc[k]);
        atomicAdd(ac + 10, rden);
    }
    __syncthreads();

    if (tid < nv) {
        float inv = 1.f / accs[tid * 11 + 10];
        #pragma unroll
        for (int k = 0; k < 10; k++) {
            float v = accs[tid * 11 + k] * inv + sbias[k];
            inbuf[tid * 25 + k] = v > 0.f ? v : 0.f;
        }
    }
    __syncthreads();

    for (int w = tid; w < BSZ * 10; w += 256) {
        int node = w / 10, word = w % 10;
        if (node >= nv) continue;
        const float* in = inbuf + node * 25;
        int jp = word % 5;
        const float* Wb = (word < 5) ? sWl2 : sWr2;
        const float* bb = (word < 5) ? sbl2 : sbr2;
        float s0 = bb[2 * jp], s1 = bb[2 * jp + 1];
        for (int k = 0; k < 25; k++) {
            float v = in[k];
            s0 += v * Wb[(2 * jp) * 25 + k];
            s1 += v * Wb[(2 * jp + 1) * 25 + k];
        }
        unsigned short* outp = ((word < 5) ? xlh_out : xrh_out) + (n0 + node) * HSTR;
        ((unsigned*)outp)[jp] = (unsigned)f2bf(s0) | ((unsigned)f2bf(s1) << 16);
    }
}

// ---------------- gather last: main loop + lane-parallel h write + value head ----------
__global__ __launch_bounds__(256, 4) void gather_last_kernel(
    const int* __restrict__ srtp, const int* __restrict__ bcounts,
    const unsigned short* __restrict__ xlh, const unsigned short* __restrict__ xrh,
    const float* __restrict__ att, const float* __restrict__ bias,
    const float* __restrict__ x1, const float* __restrict__ x2,
    const float* __restrict__ lin_W, const float* __restrict__ lin_b,
    const float* __restrict__ lin2_W, const float* __restrict__ lin2_b,
    float* __restrict__ hout, float* __restrict__ Vsum)
{
    __shared__ float accs[BSZ * 11];
    __shared__ float xrs[BSZ * 11];
    __shared__ float sat[10], sbias[10];
    __shared__ float sLW[15 * 29], sLb[15], sW2[15];
    __shared__ float inbuf[BSZ * 29];   // [node][0..9]=h, [10..24]=x1, [25..28]=x2
    __shared__ float bsum;
    __shared__ float slin2b;
    int b = blockIdx.x, tid = threadIdx.x;
    int n0 = b * BSZ;
    int nv = NN - n0; if (nv > BSZ) nv = BSZ;
    if (tid < 10) { sat[tid] = att[tid]; sbias[tid] = bias[tid]; }
    for (int i = tid; i < 15 * 29; i += 256) sLW[i] = lin_W[i];
    if (tid < 15) { sLb[tid] = lin_b[tid]; sW2[tid] = lin2_W[tid]; }
    if (tid == 0) { slin2b = lin2_b[0]; bsum = 0.f; }
    for (int i = tid; i < nv * 15; i += 256)
        inbuf[(i / 15) * 29 + 10 + (i % 15)] = x1[n0 * 15 + i];
    if (tid < 4 * BSZ && (tid >> 2) < nv) inbuf[(tid >> 2) * 29 + 25 + (tid & 3)] = x2[tid & 3];
    __syncthreads();

    if (tid < BSZ) {
        int n = n0 + tid;
        if (n < NN) {
            const unsigned short* lr = xlh + n * HSTR;
            const unsigned short* rr = xrh + n * HSTR;
            uint4 ql = *(const uint4*)lr;  unsigned ql2 = *(const unsigned*)(lr + 8);
            uint4 qr = *(const uint4*)rr;  unsigned qr2 = *(const unsigned*)(rr + 8);
            float a[10], r[10];
            unpack10(ql, ql2, a);
            unpack10(qr, qr2, r);
            #pragma unroll
            for (int k = 0; k < 10; k++) xrs[tid * 11 + k] = r[k];
            float e = 0.f;
            #pragma unroll
            for (int k = 0; k < 10; k++) {
                float t = a[k] + r[k];
                t = t > 0.f ? t : 0.2f * t;
                e += sat[k] * t;
            }
            float ex = __expf(e);
            #pragma unroll
            for (int k = 0; k < 10; k++) accs[tid * 11 + k] = ex * a[k];
            accs[tid * 11 + 10] = ex;
        } else {
            #pragma unroll
            for (int k = 0; k < 11; k++) { accs[tid * 11 + k] = 0.f; xrs[tid * 11 + k] = 0.f; }
        }
    }
    __syncthreads();

    int i0 = b * PCAP;
    int cnt = bcounts[b];
    int C = (cnt + 255) >> 8;
    int a0 = i0 + tid * C;
    int a1 = a0 + C; if (a1 > i0 + cnt) a1 = i0 + cnt;
    int len = a1 - a0; if (len < 0) len = 0;
    if (len > 0) {
        int ps[CMAX];
        #pragma unroll
        for (int i = 0; i < CMAX; i++) ps[i] = (i < len) ? srtp[a0 + i] : -1;

        const unsigned short* row0 = xlh + (ps[0] & 0x1FFFF) * HSTR;
        uint4 q = *(const uint4*)row0;
        unsigned q2 = *(const unsigned*)(row0 + 8);
        int cur = ps[0] >> 17;
        float racc[10];
        #pragma unroll
        for (int k = 0; k < 10; k++) racc[k] = 0.f;
        float rden = 0.f;
        #pragma unroll
        for (int i = 0; i < CMAX; i++) {
            if (i >= len) break;
            uint4 qn = q; unsigned q2n = q2;
            if (i + 1 < len) {
                const unsigned short* rn = xlh + (ps[i + 1] & 0x1FFFF) * HSTR;
                qn = *(const uint4*)rn;
                q2n = *(const unsigned*)(rn + 8);
            }
            int ld = ps[i] >> 17;
            if (ld != cur) {
                float* ac = accs + cur * 11;
                #pragma unroll
                for (int k = 0; k < 10; k++) atomicAdd(ac + k, racc[k]);
                atomicAdd(ac + 10, rden);
                #pragma unroll
                for (int k = 0; k < 10; k++) racc[k] = 0.f;
                rden = 0.f;
                cur = ld;
            }
            float a[10];
            unpack10(q, q2, a);
            const float* r = xrs + ld * 11;
            float e = 0.f;
            #pragma unroll
            for (int k = 0; k < 10; k++) {
                float t = a[k] + r[k];
                t = t > 0.f ? t : 0.2f * t;
                e += sat[k] * t;
            }
            float ex = __expf(e);
            rden += ex;
            #pragma unroll
            for (int k = 0; k < 10; k++) racc[k] += ex * a[k];
            q = qn; q2 = q2n;
        }
        float* ac = accs + cur * 11;
        #pragma unroll
        for (int k = 0; k < 10; k++) atomicAdd(ac + k, racc[k]);
        atomicAdd(ac + 10, rden);
    }
    __syncthreads();

    if (tid < nv) {
        float inv = 1.f / accs[tid * 11 + 10];
        #pragma unroll
        for (int k = 0; k < 10; k++) {
            float v = accs[tid * 11 + k] * inv + sbias[k];
            inbuf[tid * 29 + k] = v > 0.f ? v : 0.f;
        }
    }
    __syncthreads();

    for (int w = tid; w < BSZ * 10; w += 256) {
        int node = w / 10, k = w % 10;
        if (node < nv) hout[(n0 + node) * STR + k] = inbuf[node * 29 + k];
    }
    for (int w = tid; w < BSZ * 15; w += 256) {
        int node = w / 15, j = w % 15;
        if (node >= nv) continue;
        const float* in = inbuf + node * 29;
        float s = sLb[j];
        for (int k = 0; k < 29; k++) s += in[k] * sLW[j * 29 + k];
        if (s > 0.f) atomicAdd(&bsum, s * sW2[j]);
    }
    __syncthreads();
    if (tid == 0) atomicAdd(Vsum, bsum + (float)nv * slin2b);
}

// ---------------- fused order head + softmax + V output (single block) ----------------
__global__ __launch_bounds__(256) void orders_final_kernel(
    const float* __restrict__ x, const float* __restrict__ x1,
    const int* __restrict__ move_type, const int* __restrict__ m_src,
    const int* __restrict__ m_dst, const int* __restrict__ m_target,
    const float* __restrict__ m_armies, const int* __restrict__ move_id,
    const float* __restrict__ aaa_W, const float* __restrict__ aaa_b,
    const float* __restrict__ ccc_W, const float* __restrict__ ccc_b,
    const float* __restrict__ attl_W, const float* __restrict__ attl_b,
    const float* __restrict__ pi_W, const float* __restrict__ pi_b,
    const float* __restrict__ Vsum, float* __restrict__ out)
{
    __shared__ float sA[20 * 48], sC[20 * 23], sAb[20], sCb[20], sAt[20], sPi[20];
    __shared__ float al_s[TT], piv_s[TT];
    __shared__ float amax_s[MM], den_s[MM], num_s[MM];
    __shared__ float sh[256];
    __shared__ float s_max, s_sum;
    int tid = threadIdx.x;
    for (int i = tid; i < 20 * 48; i += 256) sA[i] = aaa_W[i];
    for (int i = tid; i < 20 * 23; i += 256) sC[i] = ccc_W[i];
    if (tid < 20) { sAb[tid] = aaa_b[tid]; sCb[tid] = ccc_b[tid];
                    sAt[tid] = attl_W[tid]; sPi[tid] = pi_W[tid]; }
    amax_s[tid] = -INFINITY; den_s[tid] = 0.f; num_s[tid] = 0.f;
    __syncthreads();

    float ab = attl_b[0], pb = pi_b[0];
    for (int t = tid; t < TT; t += 256) {
        float armies = m_armies[t];
        float hm[20];
        if (move_type[t] == 0) {
            int sn = m_src[t], dn = m_dst[t];
            float f[48];
            #pragma unroll
            for (int k = 0; k < 10; k++) f[k] = x[sn * STR + k];
            #pragma unroll
            for (int k = 0; k < 10; k++) f[10 + k] = x[dn * STR + k];
            #pragma unroll
            for (int k = 0; k < 12; k++) f[20 + k] = x1[sn * 15 + 3 + k];
            #pragma unroll
            for (int k = 0; k < 14; k++) f[32 + k] = x1[dn * 15 + 1 + k];
            f[46] = armies;
            f[47] = 0.6f * armies - 0.7f * (x1[dn * 15 + 3] + x1[dn * 15 + 4]);
            #pragma unroll
            for (int j = 0; j < 20; j++) {
                float s = sAb[j];
                for (int k = 0; k < 48; k++) s += f[k] * sA[j * 48 + k];
                hm[j] = s > 0.f ? s : 0.f;
            }
        } else {
            int tg = m_target[t];
            float f[23];
            #pragma unroll
            for (int k = 0; k < 10; k++) f[k] = x[tg * STR + k];
            #pragma unroll
            for (int k = 0; k < 12; k++) f[10 + k] = x1[tg * 15 + 3 + k];
            f[22] = armies;
            #pragma unroll
            for (int j = 0; j < 20; j++) {
                float s = sCb[j];
                for (int k = 0; k < 23; k++) s += f[k] * sC[j * 23 + k];
                hm[j] = s > 0.f ? s : 0.f;
            }
        }
        float a = ab, p = pb;
        #pragma unroll
        for (int j = 0; j < 20; j++) { a += hm[j] * sAt[j]; p += hm[j] * sPi[j]; }
        al_s[t] = a;
        piv_s[t] = p;
        atomicMaxF(&amax_s[move_id[t]], a);
    }
    __syncthreads();

    for (int t = tid; t < TT; t += 256) {
        int mid = move_id[t];
        float ex = __expf(al_s[t] - amax_s[mid]);
        atomicAdd(&den_s[mid], ex);
        atomicAdd(&num_s[mid], ex * piv_s[t]);
    }
    __syncthreads();

    float p = num_s[tid] / den_s[tid];
    sh[tid] = p;
    __syncthreads();
    for (int off = 128; off > 0; off >>= 1) {
        if (tid < off) sh[tid] = fmaxf(sh[tid], sh[tid + off]);
        __syncthreads();
    }
    if (tid == 0) s_max = sh[0];
    __syncthreads();
    float e = __expf(p - s_max);
    sh[tid] = e;
    __syncthreads();
    for (int off = 128; off > 0; off >>= 1) {
        if (tid < off) sh[tid] += sh[tid + off];
        __syncthreads();
    }
    if (tid == 0) s_sum = sh[0];
    __syncthreads();
    out[1 + tid] = p - s_max - logf(s_sum);
    if (tid == 0) out[0] = tanhf(Vsum[0] / (float)NN);
}

extern "C" void kernel_launch(void* const* d_in, const int* in_sizes, int n_in,
                              void* d_out, int out_size, void* d_ws, size_t ws_size,
                              hipStream_t stream) {
    const float* x1        = (const float*)d_in[0];
    const float* x2        = (const float*)d_in[1];
    const int*   esrc      = (const int*)d_in[2];
    const int*   edst      = (const int*)d_in[3];
    const int*   move_type = (const int*)d_in[4];
    const int*   m_src     = (const int*)d_in[5];
    const int*   m_dst     = (const int*)d_in[6];
    const int*   m_target  = (const int*)d_in[7];
    const float* m_armies  = (const float*)d_in[8];
    const int*   move_id   = (const int*)d_in[9];
    const float* W[3][6];
    for (int l = 0; l < 3; l++)
        for (int j = 0; j < 6; j++)
            W[l][j] = (const float*)d_in[10 + l * 6 + j];
    const float* lin_W  = (const float*)d_in[28];
    const float* lin_b  = (const float*)d_in[29];
    const float* lin2_W = (const float*)d_in[30];
    const float* lin2_b = (const float*)d_in[31];
    const float* aaa_W  = (const float*)d_in[32];
    const float* aaa_b  = (const float*)d_in[33];
    const float* ccc_W  = (const float*)d_in[34];
    const float* ccc_b  = (const float*)d_in[35];
    const float* attl_W = (const float*)d_in[36];
    const float* attl_b = (const float*)d_in[37];
    const float* pi_W   = (const float*)d_in[38];
    const float* pi_b   = (const float*)d_in[39];

    // workspace layout (~45 MB)
    float* ws = (float*)d_ws;
    float* hA    = ws; ws += NN * STR;
    float* Vsum  = ws; ws += 1;
    unsigned short* xlhA = (unsigned short*)ws; ws += NN * HSTR / 2;
    unsigned short* xrhA = (unsigned short*)ws; ws += NN * HSTR / 2;
    unsigned short* xlhB = (unsigned short*)ws; ws += NN * HSTR / 2;
    unsigned short* xrhB = (unsigned short*)ws; ws += NN * HSTR / 2;
    int* iws = (int*)ws;
    int* pcursor = iws; iws += NB;
    int* bcounts = iws; iws += NB;
    int* srtp    = iws; iws += NB * PCAP;

    dim3 blk(256);
    dim3 gN((NN + 255) / 256);

    // 7 dispatches total
    init_prep1_kernel<<<gN, blk, 0, stream>>>(x1, W[0][0], W[0][1], W[0][2], W[0][3],
                                              xlhA, xrhA, pcursor, Vsum);
    scatter_kernel<<<dim3(NBLK), dim3(1024), 0, stream>>>(esrc, edst, pcursor, srtp);
    sort2_kernel<<<dim3(NB), dim3(512), 0, stream>>>(srtp, pcursor, bcounts);

    // layer 1 gather + fused layer-2 prep (A -> B)
    gather_mid_kernel<<<dim3(NB), blk, 0, stream>>>(srtp, bcounts, xlhA, xrhA,
                                                    W[0][4], W[0][5], x1,
                                                    W[1][0], W[1][1], W[1][2], W[1][3],
                                                    xlhB, xrhB);
    // layer 2 gather + fused layer-3 prep (B -> A)
    gather_mid_kernel<<<dim3(NB), blk, 0, stream>>>(srtp, bcounts, xlhB, xrhB,
                                                    W[1][4], W[1][5], x1,
                                                    W[2][0], W[2][1], W[2][2], W[2][3],
                                                    xlhA, xrhA);
    // layer 3 gather + hA write + fused value head (A)
    gather_last_kernel<<<dim3(NB), blk, 0, stream>>>(srtp, bcounts, xlhA, xrhA,
                                                     W[2][4], W[2][5], x1, x2,
                                                     lin_W, lin_b, lin2_W, lin2_b,
                                                     hA, Vsum);

    // fused order head + log_softmax + V (single block)
    orders_final_kernel<<<dim3(1), blk, 0, stream>>>(hA, x1, move_type, m_src, m_dst,
                                                     m_target, m_armies, move_id,
                                                     aaa_W, aaa_b, ccc_W, ccc_b,
                                                     attl_W, attl_b, pi_W, pi_b,
                                                     Vsum, (float*)d_out);
}

// Round 17
// 400.431 us; speedup vs baseline: 1.3166x; 1.3166x over previous
//
#include <hip/hip_runtime.h>
#include <cmath>

#define NN 100000
#define NE 3200000
#define TT 2048
#define MM 256
#define STR 16    // padded row stride (floats) for fp32 node arrays -> 64B rows
#define HSTR 16   // row stride (ushorts) for bf16 rows -> 32B, 3.2MB/array
#define BSZ 64    // nodes per bucket
#define NB 1563   // ceil(NN/BSZ)
#define EPB 16384 // edges per scatter block
#define NBLK 196  // ceil(NE/EPB)
#define SCAP 3072 // max valid edges per bucket (mean 2048, 12+ sigma margin)
#define PCAP 4096 // fixed padded region per bucket in srtp (padded mean ~3126)
#define CMAX 12   // max edges per lane chunk in gather

__device__ __forceinline__ void atomicMaxF(float* addr, float v) {
    if (v >= 0.f) atomicMax((int*)addr, __float_as_int(v));
    else          atomicMin((unsigned int*)addr, __float_as_uint(v));
}

__device__ __forceinline__ unsigned short f2bf(float x) {
    unsigned u = __float_as_uint(x);
    u += 0x7FFFu + ((u >> 16) & 1u);   // round-to-nearest-even
    return (unsigned short)(u >> 16);
}

__device__ __forceinline__ void unpack10(uint4 q, unsigned q2, float* a) {
    a[0] = __uint_as_float(q.x << 16);
    a[1] = __uint_as_float(q.x & 0xFFFF0000u);
    a[2] = __uint_as_float(q.y << 16);
    a[3] = __uint_as_float(q.y & 0xFFFF0000u);
    a[4] = __uint_as_float(q.z << 16);
    a[5] = __uint_as_float(q.z & 0xFFFF0000u);
    a[6] = __uint_as_float(q.w << 16);
    a[7] = __uint_as_float(q.w & 0xFFFF0000u);
    a[8] = __uint_as_float(q2 << 16);
    a[9] = __uint_as_float(q2 & 0xFFFF0000u);
}

// ---------------- init (pcursor/amax/Vsum) + layer-1 prep fused ----------------
__global__ __launch_bounds__(256) void init_prep1_kernel(
    const float* __restrict__ x1,
    const float* __restrict__ Wl, const float* __restrict__ bl,
    const float* __restrict__ Wr, const float* __restrict__ br,
    unsigned short* __restrict__ xlh, unsigned short* __restrict__ xrh,
    int* __restrict__ pcursor, float* __restrict__ amax, float* __restrict__ Vsum)
{
    __shared__ float sWl[150], sWr[150], sbl[10], sbr[10];
    int tid = threadIdx.x;
    for (int i = tid; i < 150; i += 256) { sWl[i] = Wl[i]; sWr[i] = Wr[i]; }
    if (tid < 10) { sbl[tid] = bl[tid]; sbr[tid] = br[tid]; }
    __syncthreads();
    int gid = blockIdx.x * 256 + tid;
    if (gid < NB) pcursor[gid] = gid * PCAP;
    if (gid < MM) amax[gid] = -INFINITY;
    if (gid == 0) Vsum[0] = 0.f;
    int n = gid;
    if (n >= NN) return;

    float in[15];
    #pragma unroll
    for (int k = 0; k < 15; k++) in[k] = x1[n * 15 + k];

    unsigned* lp = (unsigned*)(xlh + n * HSTR);
    unsigned* rp = (unsigned*)(xrh + n * HSTR);
    #pragma unroll
    for (int jp = 0; jp < 5; jp++) {
        float sl0 = sbl[2 * jp], sr0 = sbr[2 * jp];
        float sl1 = sbl[2 * jp + 1], sr1 = sbr[2 * jp + 1];
        for (int k = 0; k < 15; k++) {
            float v = in[k];
            sl0 += v * sWl[(2 * jp) * 15 + k];
            sr0 += v * sWr[(2 * jp) * 15 + k];
            sl1 += v * sWl[(2 * jp + 1) * 15 + k];
            sr1 += v * sWr[(2 * jp + 1) * 15 + k];
        }
        lp[jp] = (unsigned)f2bf(sl0) | ((unsigned)f2bf(sl1) << 16);
        rp[jp] = (unsigned)f2bf(sr0) | ((unsigned)f2bf(sr1) << 16);
    }
}

// ---------------- scatter: LDS counting-sort by bucket, burst int4 writes ----------
__global__ __launch_bounds__(1024) void scatter_kernel(const int* __restrict__ src,
                                                       const int* __restrict__ dst,
                                                       int* __restrict__ pcursor,
                                                       int* __restrict__ srtp) {
    __shared__ int ent[EPB];
    __shared__ int cnt[NB];
    __shared__ int cur[NB];
    __shared__ int gbase[NB];
    __shared__ int psc[1024];
    int tid = threadIdx.x;
    for (int i = tid; i < NB; i += 1024) cnt[i] = 0;
    __syncthreads();
    int base = blockIdx.x * EPB;
    int end = base + EPB; if (end > NE) end = NE;
    for (int i = base + tid * 4; i < end; i += 4096) {
        int4 d4 = *(const int4*)(dst + i);
        atomicAdd(&cnt[d4.x >> 6], 1);
        atomicAdd(&cnt[d4.y >> 6], 1);
        atomicAdd(&cnt[d4.z >> 6], 1);
        atomicAdd(&cnt[d4.w >> 6], 1);
    }
    __syncthreads();
    const int PT = (NB + 1023) / 1024;  // 2
    int t0 = tid * PT;
    int s = 0;
    #pragma unroll
    for (int j = 0; j < PT; j++) { int idx = t0 + j; if (idx < NB) s += cnt[idx]; }
    psc[tid] = s;
    __syncthreads();
    for (int off = 1; off < 1024; off <<= 1) {
        int v = (tid >= off) ? psc[tid - off] : 0;
        __syncthreads();
        psc[tid] += v;
        __syncthreads();
    }
    int run = psc[tid] - s;
    #pragma unroll
    for (int j = 0; j < PT; j++) {
        int idx = t0 + j;
        if (idx < NB) { cur[idx] = run; run += cnt[idx]; }
    }
    for (int b = tid; b < NB; b += 1024) {
        int n = cnt[b];
        gbase[b] = n ? atomicAdd(&pcursor[b], (n + 15) & ~15) : 0;
    }
    __syncthreads();
    for (int i = base + tid * 4; i < end; i += 4096) {
        int4 d4 = *(const int4*)(dst + i);
        int4 s4 = *(const int4*)(src + i);
        int d, b, off;
        d = d4.x; b = d >> 6; off = atomicAdd(&cur[b], 1); ent[off] = ((d & 63) << 17) | s4.x;
        d = d4.y; b = d >> 6; off = atomicAdd(&cur[b], 1); ent[off] = ((d & 63) << 17) | s4.y;
        d = d4.z; b = d >> 6; off = atomicAdd(&cur[b], 1); ent[off] = ((d & 63) << 17) | s4.z;
        d = d4.w; b = d >> 6; off = atomicAdd(&cur[b], 1); ent[off] = ((d & 63) << 17) | s4.w;
    }
    __syncthreads();
    for (int b = tid; b < NB; b += 1024) {
        int n = cnt[b];
        if (!n) continue;
        int lb = cur[b] - n;
        int gb = gbase[b];
        int p16 = (n + 15) & ~15;
        for (int k = 0; k < p16; k += 4) {
            int4 v;
            v.x = (k + 0 < n) ? ent[lb + k + 0] : -1;
            v.y = (k + 1 < n) ? ent[lb + k + 1] : -1;
            v.z = (k + 2 < n) ? ent[lb + k + 2] : -1;
            v.w = (k + 3 < n) ? ent[lb + k + 3] : -1;
            *(int4*)(srtp + gb + k) = v;
        }
    }
}

// ---------------- sort2: in-LDS counting sort by local dst, compact IN PLACE ----------
__global__ __launch_bounds__(512) void sort2_kernel(int* __restrict__ srtp,
                                                    const int* __restrict__ pcursor,
                                                    int* __restrict__ bcounts) {
    __shared__ int ent[PCAP];
    __shared__ int ent2[SCAP];
    __shared__ int cnts[BSZ];
    __shared__ int curs[BSZ];
    int b = blockIdx.x, tid = threadIdx.x;
    int p0 = b * PCAP;
    int pcnt = pcursor[b] - p0;
    if (pcnt > PCAP) pcnt = PCAP;
    if (tid < BSZ) cnts[tid] = 0;
    __syncthreads();
    for (int i = tid; i < pcnt; i += 512) {
        int p = srtp[p0 + i];
        ent[i] = p;
        if (p >= 0) atomicAdd(&cnts[p >> 17], 1);
    }
    __syncthreads();
    if (tid == 0) {
        int run = 0;
        for (int k = 0; k < BSZ; k++) { curs[k] = run; run += cnts[k]; }
    }
    __syncthreads();
    for (int i = tid; i < pcnt; i += 512) {
        int p = ent[i];
        if (p >= 0) {
            int pos = atomicAdd(&curs[p >> 17], 1);
            ent2[pos] = p;
        }
    }
    __syncthreads();
    int cnt = curs[BSZ - 1];   // total valid
    for (int i = tid; i < cnt; i += 512) srtp[p0 + i] = ent2[i];
    if (tid == 0) bcounts[b] = cnt;
}

// ---------------- gather mid: R10 main loop (depth-1) + lane-parallel fused prep ----
__global__ __launch_bounds__(256, 4) void gather_mid_kernel(
    const int* __restrict__ srtp, const int* __restrict__ bcounts,
    const unsigned short* __restrict__ xlh, const unsigned short* __restrict__ xrh,
    const float* __restrict__ att, const float* __restrict__ bias,
    const float* __restrict__ x1,
    const float* __restrict__ Wl2, const float* __restrict__ bl2,
    const float* __restrict__ Wr2, const float* __restrict__ br2,
    unsigned short* __restrict__ xlh_out, unsigned short* __restrict__ xrh_out)
{
    __shared__ float accs[BSZ * 11];
    __shared__ float xrs[BSZ * 11];
    __shared__ float sat[10], sbias[10];
    __shared__ float sWl2[250], sWr2[250], sbl2[10], sbr2[10];
    __shared__ float inbuf[BSZ * 25];   // [node][0..9]=h, [10..24]=x1
    int b = blockIdx.x, tid = threadIdx.x;
    int n0 = b * BSZ;
    int nv = NN - n0; if (nv > BSZ) nv = BSZ;
    if (tid < 10) { sat[tid] = att[tid]; sbias[tid] = bias[tid];
                    sbl2[tid] = bl2[tid]; sbr2[tid] = br2[tid]; }
    for (int i = tid; i < 250; i += 256) { sWl2[i] = Wl2[i]; sWr2[i] = Wr2[i]; }
    for (int i = tid; i < nv * 15; i += 256)
        inbuf[(i / 15) * 25 + 10 + (i % 15)] = x1[n0 * 15 + i];
    __syncthreads();

    if (tid < BSZ) {
        int n = n0 + tid;
        if (n < NN) {
            const unsigned short* lr = xlh + n * HSTR;
            const unsigned short* rr = xrh + n * HSTR;
            uint4 ql = *(const uint4*)lr;  unsigned ql2 = *(const unsigned*)(lr + 8);
            uint4 qr = *(const uint4*)rr;  unsigned qr2 = *(const unsigned*)(rr + 8);
            float a[10], r[10];
            unpack10(ql, ql2, a);
            unpack10(qr, qr2, r);
            #pragma unroll
            for (int k = 0; k < 10; k++) xrs[tid * 11 + k] = r[k];
            float e = 0.f;
            #pragma unroll
            for (int k = 0; k < 10; k++) {
                float t = a[k] + r[k];
                t = t > 0.f ? t : 0.2f * t;
                e += sat[k] * t;
            }
            float ex = __expf(e);
            #pragma unroll
            for (int k = 0; k < 10; k++) accs[tid * 11 + k] = ex * a[k];
            accs[tid * 11 + 10] = ex;
        } else {
            #pragma unroll
            for (int k = 0; k < 11; k++) { accs[tid * 11 + k] = 0.f; xrs[tid * 11 + k] = 0.f; }
        }
    }
    __syncthreads();

    int i0 = b * PCAP;
    int cnt = bcounts[b];
    int C = (cnt + 255) >> 8;
    int a0 = i0 + tid * C;
    int a1 = a0 + C; if (a1 > i0 + cnt) a1 = i0 + cnt;
    int len = a1 - a0; if (len < 0) len = 0;
    if (len > 0) {
        int ps[CMAX];
        #pragma unroll
        for (int i = 0; i < CMAX; i++) ps[i] = (i < len) ? srtp[a0 + i] : -1;

        const unsigned short* row0 = xlh + (ps[0] & 0x1FFFF) * HSTR;
        uint4 q = *(const uint4*)row0;
        unsigned q2 = *(const unsigned*)(row0 + 8);
        int cur = ps[0] >> 17;
        float racc[10];
        #pragma unroll
        for (int k = 0; k < 10; k++) racc[k] = 0.f;
        float rden = 0.f;
        #pragma unroll
        for (int i = 0; i < CMAX; i++) {
            if (i >= len) break;
            uint4 qn = q; unsigned q2n = q2;
            if (i + 1 < len) {
                const unsigned short* rn = xlh + (ps[i + 1] & 0x1FFFF) * HSTR;
                qn = *(const uint4*)rn;
                q2n = *(const unsigned*)(rn + 8);
            }
            int ld = ps[i] >> 17;
            if (ld != cur) {
                float* ac = accs + cur * 11;
                #pragma unroll
                for (int k = 0; k < 10; k++) atomicAdd(ac + k, racc[k]);
                atomicAdd(ac + 10, rden);
                #pragma unroll
                for (int k = 0; k < 10; k++) racc[k] = 0.f;
                rden = 0.f;
                cur = ld;
            }
            float a[10];
            unpack10(q, q2, a);
            const float* r = xrs + ld * 11;
            float e = 0.f;
            #pragma unroll
            for (int k = 0; k < 10; k++) {
                float t = a[k] + r[k];
                t = t > 0.f ? t : 0.2f * t;
                e += sat[k] * t;
            }
            float ex = __expf(e);
            rden += ex;
            #pragma unroll
            for (int k = 0; k < 10; k++) racc[k] += ex * a[k];
            q = qn; q2 = q2n;
        }
        float* ac = accs + cur * 11;
        #pragma unroll
        for (int k = 0; k < 10; k++) atomicAdd(ac + k, racc[k]);
        atomicAdd(ac + 10, rden);
    }
    __syncthreads();

    if (tid < nv) {
        float inv = 1.f / accs[tid * 11 + 10];
        #pragma unroll
        for (int k = 0; k < 10; k++) {
            float v = accs[tid * 11 + k] * inv + sbias[k];
            inbuf[tid * 25 + k] = v > 0.f ? v : 0.f;
        }
    }
    __syncthreads();

    for (int w = tid; w < BSZ * 10; w += 256) {
        int node = w / 10, word = w % 10;
        if (node >= nv) continue;
        const float* in = inbuf + node * 25;
        int jp = word % 5;
        const float* Wb = (word < 5) ? sWl2 : sWr2;
        const float* bb = (word < 5) ? sbl2 : sbr2;
        float s0 = bb[2 * jp], s1 = bb[2 * jp + 1];
        for (int k = 0; k < 25; k++) {
            float v = in[k];
            s0 += v * Wb[(2 * jp) * 25 + k];
            s1 += v * Wb[(2 * jp + 1) * 25 + k];
        }
        unsigned short* outp = ((word < 5) ? xlh_out : xrh_out) + (n0 + node) * HSTR;
        ((unsigned*)outp)[jp] = (unsigned)f2bf(s0) | ((unsigned)f2bf(s1) << 16);
    }
}

// ---------------- gather last: main loop + lane-parallel h write + value head ----------
__global__ __launch_bounds__(256, 4) void gather_last_kernel(
    const int* __restrict__ srtp, const int* __restrict__ bcounts,
    const unsigned short* __restrict__ xlh, const unsigned short* __restrict__ xrh,
    const float* __restrict__ att, const float* __restrict__ bias,
    const float* __restrict__ x1, const float* __restrict__ x2,
    const float* __restrict__ lin_W, const float* __restrict__ lin_b,
    const float* __restrict__ lin2_W, const float* __restrict__ lin2_b,
    float* __restrict__ hout, float* __restrict__ Vsum)
{
    __shared__ float accs[BSZ * 11];
    __shared__ float xrs[BSZ * 11];
    __shared__ float sat[10], sbias[10];
    __shared__ float sLW[15 * 29], sLb[15], sW2[15];
    __shared__ float inbuf[BSZ * 29];   // [node][0..9]=h, [10..24]=x1, [25..28]=x2
    __shared__ float bsum;
    __shared__ float slin2b;
    int b = blockIdx.x, tid = threadIdx.x;
    int n0 = b * BSZ;
    int nv = NN - n0; if (nv > BSZ) nv = BSZ;
    if (tid < 10) { sat[tid] = att[tid]; sbias[tid] = bias[tid]; }
    for (int i = tid; i < 15 * 29; i += 256) sLW[i] = lin_W[i];
    if (tid < 15) { sLb[tid] = lin_b[tid]; sW2[tid] = lin2_W[tid]; }
    if (tid == 0) { slin2b = lin2_b[0]; bsum = 0.f; }
    for (int i = tid; i < nv * 15; i += 256)
        inbuf[(i / 15) * 29 + 10 + (i % 15)] = x1[n0 * 15 + i];
    if (tid < 4 * BSZ && (tid >> 2) < nv) inbuf[(tid >> 2) * 29 + 25 + (tid & 3)] = x2[tid & 3];
    __syncthreads();

    if (tid < BSZ) {
        int n = n0 + tid;
        if (n < NN) {
            const unsigned short* lr = xlh + n * HSTR;
            const unsigned short* rr = xrh + n * HSTR;
            uint4 ql = *(const uint4*)lr;  unsigned ql2 = *(const unsigned*)(lr + 8);
            uint4 qr = *(const uint4*)rr;  unsigned qr2 = *(const unsigned*)(rr + 8);
            float a[10], r[10];
            unpack10(ql, ql2, a);
            unpack10(qr, qr2, r);
            #pragma unroll
            for (int k = 0; k < 10; k++) xrs[tid * 11 + k] = r[k];
            float e = 0.f;
            #pragma unroll
            for (int k = 0; k < 10; k++) {
                float t = a[k] + r[k];
                t = t > 0.f ? t : 0.2f * t;
                e += sat[k] * t;
            }
            float ex = __expf(e);
            #pragma unroll
            for (int k = 0; k < 10; k++) accs[tid * 11 + k] = ex * a[k];
            accs[tid * 11 + 10] = ex;
        } else {
            #pragma unroll
            for (int k = 0; k < 11; k++) { accs[tid * 11 + k] = 0.f; xrs[tid * 11 + k] = 0.f; }
        }
    }
    __syncthreads();

    int i0 = b * PCAP;
    int cnt = bcounts[b];
    int C = (cnt + 255) >> 8;
    int a0 = i0 + tid * C;
    int a1 = a0 + C; if (a1 > i0 + cnt) a1 = i0 + cnt;
    int len = a1 - a0; if (len < 0) len = 0;
    if (len > 0) {
        int ps[CMAX];
        #pragma unroll
        for (int i = 0; i < CMAX; i++) ps[i] = (i < len) ? srtp[a0 + i] : -1;

        const unsigned short* row0 = xlh + (ps[0] & 0x1FFFF) * HSTR;
        uint4 q = *(const uint4*)row0;
        unsigned q2 = *(const unsigned*)(row0 + 8);
        int cur = ps[0] >> 17;
        float racc[10];
        #pragma unroll
        for (int k = 0; k < 10; k++) racc[k] = 0.f;
        float rden = 0.f;
        #pragma unroll
        for (int i = 0; i < CMAX; i++) {
            if (i >= len) break;
            uint4 qn = q; unsigned q2n = q2;
            if (i + 1 < len) {
                const unsigned short* rn = xlh + (ps[i + 1] & 0x1FFFF) * HSTR;
                qn = *(const uint4*)rn;
                q2n = *(const unsigned*)(rn + 8);
            }
            int ld = ps[i] >> 17;
            if (ld != cur) {
                float* ac = accs + cur * 11;
                #pragma unroll
                for (int k = 0; k < 10; k++) atomicAdd(ac + k, racc[k]);
                atomicAdd(ac + 10, rden);
                #pragma unroll
                for (int k = 0; k < 10; k++) racc[k] = 0.f;
                rden = 0.f;
                cur = ld;
            }
            float a[10];
            unpack10(q, q2, a);
            const float* r = xrs + ld * 11;
            float e = 0.f;
            #pragma unroll
            for (int k = 0; k < 10; k++) {
                float t = a[k] + r[k];
                t = t > 0.f ? t : 0.2f * t;
                e += sat[k] * t;
            }
            float ex = __expf(e);
            rden += ex;
            #pragma unroll
            for (int k = 0; k < 10; k++) racc[k] += ex * a[k];
            q = qn; q2 = q2n;
        }
        float* ac = accs + cur * 11;
        #pragma unroll
        for (int k = 0; k < 10; k++) atomicAdd(ac + k, racc[k]);
        atomicAdd(ac + 10, rden);
    }
    __syncthreads();

    if (tid < nv) {
        float inv = 1.f / accs[tid * 11 + 10];
        #pragma unroll
        for (int k = 0; k < 10; k++) {
            float v = accs[tid * 11 + k] * inv + sbias[k];
            inbuf[tid * 29 + k] = v > 0.f ? v : 0.f;
        }
    }
    __syncthreads();

    for (int w = tid; w < BSZ * 10; w += 256) {
        int node = w / 10, k = w % 10;
        if (node < nv) hout[(n0 + node) * STR + k] = inbuf[node * 29 + k];
    }
    for (int w = tid; w < BSZ * 15; w += 256) {
        int node = w / 15, j = w % 15;
        if (node >= nv) continue;
        const float* in = inbuf + node * 29;
        float s = sLb[j];
        for (int k = 0; k < 29; k++) s += in[k] * sLW[j * 29 + k];
        if (s > 0.f) atomicAdd(&bsum, s * sW2[j]);
    }
    __syncthreads();
    if (tid == 0) atomicAdd(Vsum, bsum + (float)nv * slin2b);
}

// ---------------- order head, stage 1 (full-grid: 8 blocks, one order/lane) ----------
__global__ __launch_bounds__(256) void orders_kernel(
    const float* __restrict__ x, const float* __restrict__ x1,
    const int* __restrict__ move_type, const int* __restrict__ m_src,
    const int* __restrict__ m_dst, const int* __restrict__ m_target,
    const float* __restrict__ m_armies, const int* __restrict__ move_id,
    const float* __restrict__ aaa_W, const float* __restrict__ aaa_b,
    const float* __restrict__ ccc_W, const float* __restrict__ ccc_b,
    const float* __restrict__ attl_W, const float* __restrict__ attl_b,
    const float* __restrict__ pi_W, const float* __restrict__ pi_b,
    float* __restrict__ al_out, float* __restrict__ pi_out, float* __restrict__ amax)
{
    __shared__ float sA[20 * 48], sC[20 * 23], sAb[20], sCb[20];
    int tid = threadIdx.x;
    for (int i = tid; i < 20 * 48; i += 256) sA[i] = aaa_W[i];
    for (int i = tid; i < 20 * 23; i += 256) sC[i] = ccc_W[i];
    if (tid < 20) { sAb[tid] = aaa_b[tid]; sCb[tid] = ccc_b[tid]; }
    __syncthreads();
    int t = blockIdx.x * 256 + tid;
    if (t >= TT) return;

    float armies = m_armies[t];
    float hm[20];
    if (move_type[t] == 0) {
        int sn = m_src[t], dn = m_dst[t];
        float f[48];
        #pragma unroll
        for (int k = 0; k < 10; k++) f[k] = x[sn * STR + k];
        #pragma unroll
        for (int k = 0; k < 10; k++) f[10 + k] = x[dn * STR + k];
        #pragma unroll
        for (int k = 0; k < 12; k++) f[20 + k] = x1[sn * 15 + 3 + k];
        #pragma unroll
        for (int k = 0; k < 14; k++) f[32 + k] = x1[dn * 15 + 1 + k];
        f[46] = armies;
        f[47] = 0.6f * armies - 0.7f * (x1[dn * 15 + 3] + x1[dn * 15 + 4]);
        #pragma unroll
        for (int j = 0; j < 20; j++) {
            float s = sAb[j];
            for (int k = 0; k < 48; k++) s += f[k] * sA[j * 48 + k];
            hm[j] = s > 0.f ? s : 0.f;
        }
    } else {
        int tg = m_target[t];
        float f[23];
        #pragma unroll
        for (int k = 0; k < 10; k++) f[k] = x[tg * STR + k];
        #pragma unroll
        for (int k = 0; k < 12; k++) f[10 + k] = x1[tg * 15 + 3 + k];
        f[22] = armies;
        #pragma unroll
        for (int j = 0; j < 20; j++) {
            float s = sCb[j];
            for (int k = 0; k < 23; k++) s += f[k] * sC[j * 23 + k];
            hm[j] = s > 0.f ? s : 0.f;
        }
    }
    float a = attl_b[0], p = pi_b[0];
    #pragma unroll
    for (int j = 0; j < 20; j++) { a += hm[j] * attl_W[j]; p += hm[j] * pi_W[j]; }
    al_out[t] = a;
    pi_out[t] = p;
    atomicMaxF(&amax[move_id[t]], a);
}

// ---------------- fused: segment exp-sums (LDS) + log_softmax + V ----------------
__global__ __launch_bounds__(256) void final2_kernel(
    const float* __restrict__ al, const float* __restrict__ piv,
    const int* __restrict__ move_id, const float* __restrict__ amax,
    const float* __restrict__ Vsum, float* __restrict__ out)
{
    __shared__ float den_s[MM], num_s[MM];
    __shared__ float sh[256];
    __shared__ float s_max, s_sum;
    int m = threadIdx.x;
    den_s[m] = 0.f; num_s[m] = 0.f;
    __syncthreads();
    for (int t = m; t < TT; t += 256) {
        int mid = move_id[t];
        float ex = __expf(al[t] - amax[mid]);
        atomicAdd(&den_s[mid], ex);
        atomicAdd(&num_s[mid], ex * piv[t]);
    }
    __syncthreads();
    float p = num_s[m] / den_s[m];
    sh[m] = p;
    __syncthreads();
    for (int off = 128; off > 0; off >>= 1) {
        if (m < off) sh[m] = fmaxf(sh[m], sh[m + off]);
        __syncthreads();
    }
    if (m == 0) s_max = sh[0];
    __syncthreads();
    float e = __expf(p - s_max);
    sh[m] = e;
    __syncthreads();
    for (int off = 128; off > 0; off >>= 1) {
        if (m < off) sh[m] += sh[m + off];
        __syncthreads();
    }
    if (m == 0) s_sum = sh[0];
    __syncthreads();
    out[1 + m] = p - s_max - logf(s_sum);
    if (m == 0) out[0] = tanhf(Vsum[0] / (float)NN);
}

extern "C" void kernel_launch(void* const* d_in, const int* in_sizes, int n_in,
                              void* d_out, int out_size, void* d_ws, size_t ws_size,
                              hipStream_t stream) {
    const float* x1        = (const float*)d_in[0];
    const float* x2        = (const float*)d_in[1];
    const int*   esrc      = (const int*)d_in[2];
    const int*   edst      = (const int*)d_in[3];
    const int*   move_type = (const int*)d_in[4];
    const int*   m_src     = (const int*)d_in[5];
    const int*   m_dst     = (const int*)d_in[6];
    const int*   m_target  = (const int*)d_in[7];
    const float* m_armies  = (const float*)d_in[8];
    const int*   move_id   = (const int*)d_in[9];
    const float* W[3][6];
    for (int l = 0; l < 3; l++)
        for (int j = 0; j < 6; j++)
            W[l][j] = (const float*)d_in[10 + l * 6 + j];
    const float* lin_W  = (const float*)d_in[28];
    const float* lin_b  = (const float*)d_in[29];
    const float* lin2_W = (const float*)d_in[30];
    const float* lin2_b = (const float*)d_in[31];
    const float* aaa_W  = (const float*)d_in[32];
    const float* aaa_b  = (const float*)d_in[33];
    const float* ccc_W  = (const float*)d_in[34];
    const float* ccc_b  = (const float*)d_in[35];
    const float* attl_W = (const float*)d_in[36];
    const float* attl_b = (const float*)d_in[37];
    const float* pi_W   = (const float*)d_in[38];
    const float* pi_b   = (const float*)d_in[39];

    // workspace layout (~45 MB)
    float* ws = (float*)d_ws;
    float* hA    = ws; ws += NN * STR;
    float* al    = ws; ws += TT;
    float* piv   = ws; ws += TT;
    float* amax  = ws; ws += MM;
    float* Vsum  = ws; ws += 1;
    unsigned short* xlhA = (unsigned short*)ws; ws += NN * HSTR / 2;
    unsigned short* xrhA = (unsigned short*)ws; ws += NN * HSTR / 2;
    unsigned short* xlhB = (unsigned short*)ws; ws += NN * HSTR / 2;
    unsigned short* xrhB = (unsigned short*)ws; ws += NN * HSTR / 2;
    int* iws = (int*)ws;
    int* pcursor = iws; iws += NB;
    int* bcounts = iws; iws += NB;
    int* srtp    = iws; iws += NB * PCAP;

    dim3 blk(256);
    dim3 gN((NN + 255) / 256);
    dim3 gT(TT / 256);

    // 8 dispatches total (R14 structure)
    init_prep1_kernel<<<gN, blk, 0, stream>>>(x1, W[0][0], W[0][1], W[0][2], W[0][3],
                                              xlhA, xrhA, pcursor, amax, Vsum);
    scatter_kernel<<<dim3(NBLK), dim3(1024), 0, stream>>>(esrc, edst, pcursor, srtp);
    sort2_kernel<<<dim3(NB), dim3(512), 0, stream>>>(srtp, pcursor, bcounts);

    // layer 1 gather + fused layer-2 prep (A -> B)
    gather_mid_kernel<<<dim3(NB), blk, 0, stream>>>(srtp, bcounts, xlhA, xrhA,
                                                    W[0][4], W[0][5], x1,
                                                    W[1][0], W[1][1], W[1][2], W[1][3],
                                                    xlhB, xrhB);
    // layer 2 gather + fused layer-3 prep (B -> A)
    gather_mid_kernel<<<dim3(NB), blk, 0, stream>>>(srtp, bcounts, xlhB, xrhB,
                                                    W[1][4], W[1][5], x1,
                                                    W[2][0], W[2][1], W[2][2], W[2][3],
                                                    xlhA, xrhA);
    // layer 3 gather + hA write + fused value head (A)
    gather_last_kernel<<<dim3(NB), blk, 0, stream>>>(srtp, bcounts, xlhA, xrhA,
                                                     W[2][4], W[2][5], x1, x2,
                                                     lin_W, lin_b, lin2_W, lin2_b,
                                                     hA, Vsum);

    orders_kernel<<<gT, blk, 0, stream>>>(hA, x1, move_type, m_src, m_dst, m_target,
                                          m_armies, move_id, aaa_W, aaa_b, ccc_W, ccc_b,
                                          attl_W, attl_b, pi_W, pi_b, al, piv, amax);
    final2_kernel<<<dim3(1), blk, 0, stream>>>(al, piv, move_id, amax, Vsum, (float*)d_out);
}